// Round 3
// baseline (116.765 us; speedup 1.0000x reference)
//
#include <hip/hip_runtime.h>

#define N2 16384
#define N1 65536

// ---- output layout (float offsets) ----
#define OUT_AIM 7225344         // 21*21*N2
#define OUT_LD  14450688        // 2*21*21*N2
#define OUT_ZRE 14450689
#define OUT_ZIM 14794753        // OUT_ZRE + 21*N2

// ---- LDS layout (float offsets), TILE_J = 64 ----
#define L_T2R  0                // [20][64]
#define L_T2I  1280
#define L_M2   2560             // [c:2][u:4][64]
#define L_SC   3072             // [idx:26][u:4][64]
//   idx 0..3  t1r[b], 4..7  t1i[b], 8..11 p1r[b], 12..15 p1i[b],
//   idx 16..19 i0r[k], 20..23 i0i[k], 24 is1r, 25 is1i
#define L_IS2R 9728             // [64]
#define L_IS2I 9792
#define L_RED  9856             // [7]
#define L_TOT  9864             // 38.5 KB

#define SC(idx, u, jl) lds[L_SC + (((idx)*4 + (u)) * 64) + (jl)]

// ---- workspace layout (byte offsets into d_ws; ws is harness-poisoned
//      every iteration by the unconditional 268MB fill — free to use) ----
//  [0,2048)      : 256 doubles  — per-block logdet partials
//  [4096,5120)   : 256 uints    — per-block "partial ready" flags
//  [8192,8196)   : 1 uint       — NEVER written: reference poison value.
// tag = ~ref differs from the poison no matter what the poison is. If ws
// is ever NOT re-poisoned, stale flags pass early but stale partials are
// bit-identical (deterministic inputs), so the result is still correct.

// packed 8-byte non-temporal store of two adjacent floats
#define NTST2(addr, v0, v1) do {                                   \
    union { float f[2]; long L; } _u; _u.f[0] = (v0); _u.f[1] = (v1); \
    __builtin_nontemporal_store(_u.L, (long*)(addr)); } while (0)

// ---- phase-2 per-row-slot machinery (3 rows per wave-group) ----
// Slot state is kept in individually named registers (no runtime-indexed
// arrays -> no scratch). p is wave-uniform per slot.
#define SLOT_PREP(s, P)                                                       \
    const int  p##s    = (P);                                                 \
    const bool is20_##s = (p##s == 20);                                       \
    const int  ap_##s  = p##s >> 2, up_##s = p##s & 3;                        \
    float ppr0_##s=0.f, ppi0_##s=0.f, ppr1_##s=0.f, ppi1_##s=0.f;             \
    float par0_##s=0.f, pai0_##s=0.f, par1_##s=0.f, pai1_##s=0.f;             \
    if (!is20_##s) {                                                          \
        const float tpr0 = lds[L_T2R + p##s*64 + c2], tpr1 = lds[L_T2R + p##s*64 + c2+1]; \
        const float tpi0 = lds[L_T2I + p##s*64 + c2], tpi1 = lds[L_T2I + p##s*64 + c2+1]; \
        ppr0_##s = tpr0*is2r0 - tpi0*is2i0;  ppi0_##s = tpr0*is2i0 + tpi0*is2r0; \
        ppr1_##s = tpr1*is2r1 - tpi1*is2i1;  ppi1_##s = tpr1*is2i1 + tpi1*is2r1; \
        if (ap_##s < 4) {                                                     \
            par0_##s = SC(8+ap_##s,  up_##s, c2);   pai0_##s = SC(12+ap_##s, up_##s, c2);   \
            par1_##s = SC(8+ap_##s,  up_##s, c2+1); pai1_##s = SC(12+ap_##s, up_##s, c2+1); \
        }                                                                     \
    }                                                                         \
    float zar0_##s=0.f, zai0_##s=0.f, zar1_##s=0.f, zai1_##s=0.f;

#define SLOT_Q(s) do {                                                        \
    float ar0, ai0, ar1, ai1;                                                 \
    if (is20_##s) {                                                           \
        if (q < 20) {                                                         \
            ar0 = -(tr0*is2r0 - ti0*is2i0);  ai0 = tr0*is2i0 + ti0*is2r0;     \
            ar1 = -(tr1*is2r1 - ti1*is2i1);  ai1 = tr1*is2i1 + ti1*is2r1;     \
        } else { ar0=is2r0; ai0=is2i0; ar1=is2r1; ai1=is2i1; }                \
    } else if (q < 20) {                                                      \
        ar0 = ppr0_##s*tr0 + ppi0_##s*ti0;  ai0 = ppi0_##s*tr0 - ppr0_##s*ti0;\
        ar1 = ppr1_##s*tr1 + ppi1_##s*ti1;  ai1 = ppi1_##s*tr1 - ppr1_##s*ti1;\
        if ((q & 3) == up_##s) {            /* + A1[ap][q>>2] scatter */      \
            const int b = q >> 2;                                             \
            if (ap_##s < 4) {                                                 \
                if (b < 4) {                                                  \
                    const float tbr0 = SC(b, up_##s, c2),   tbi0 = SC(4+b, up_##s, c2);   \
                    const float tbr1 = SC(b, up_##s, c2+1), tbi1 = SC(4+b, up_##s, c2+1); \
                    ar0 += par0_##s*tbr0 + pai0_##s*tbi0;  ai0 += pai0_##s*tbr0 - par0_##s*tbi0; \
                    ar1 += par1_##s*tbr1 + pai1_##s*tbi1;  ai1 += pai1_##s*tbr1 - par1_##s*tbi1; \
                    if (b == ap_##s) {             /* + 1/lam00 */            \
                        ar0 += SC(16+ap_##s, up_##s, c2);   ai0 += SC(20+ap_##s, up_##s, c2);   \
                        ar1 += SC(16+ap_##s, up_##s, c2+1); ai1 += SC(20+ap_##s, up_##s, c2+1); \
                    }                                                         \
                } else { ar0 -= par0_##s; ai0 -= pai0_##s; ar1 -= par1_##s; ai1 -= pai1_##s; } \
            } else {                                                          \
                if (b < 4) {                       /* -conj(P1[b]) */         \
                    ar0 -= SC(8+b, up_##s, c2);   ai0 += SC(12+b, up_##s, c2);   \
                    ar1 -= SC(8+b, up_##s, c2+1); ai1 += SC(12+b, up_##s, c2+1); \
                } else {                           /* 1/S1 */                 \
                    ar0 += SC(24, up_##s, c2);   ai0 += SC(25, up_##s, c2);   \
                    ar1 += SC(24, up_##s, c2+1); ai1 += SC(25, up_##s, c2+1); \
                }                                                             \
            }                                                                 \
        }                                                                     \
    } else { ar0 = -ppr0_##s; ai0 = -ppi0_##s; ar1 = -ppr1_##s; ai1 = -ppi1_##s; } \
    NTST2(out + (p##s*21+q)*N2 + j2,           ar0, ar1);                     \
    NTST2(out + OUT_AIM + (p##s*21+q)*N2 + j2, ai0, ai1);                     \
    zar0_##s += zr2.x*ar0 - zi2.x*ai0;  zai0_##s += zr2.x*ai0 + zi2.x*ar0;    \
    zar1_##s += zr2.y*ar1 - zi2.y*ai1;  zai1_##s += zr2.y*ai1 + zi2.y*ar1;    \
} while (0)

#define SLOT_ZSTORE(s) do {                                                   \
    float a0 = zar0_##s, b0 = zai0_##s, a1 = zar1_##s, b1 = zai1_##s;         \
    a0 += __shfl_xor(a0, 32, 64);  b0 += __shfl_xor(b0, 32, 64);              \
    a1 += __shfl_xor(a1, 32, 64);  b1 += __shfl_xor(b1, 32, 64);              \
    const int src = l >> 1;                                                   \
    const float e_r = __shfl(a0, src, 64), o_r = __shfl(a1, src, 64);         \
    const float e_i = __shfl(b0, src, 64), o_i = __shfl(b1, src, 64);         \
    const float zvr = (l & 1) ? o_r : e_r;                                    \
    const float zvi = (l & 1) ? o_i : e_i;                                    \
    __builtin_nontemporal_store(zvr, out + OUT_ZRE + p##s*N2 + j0 + l);       \
    __builtin_nontemporal_store(zvi, out + OUT_ZIM + p##s*N2 + j0 + l);       \
} while (0)

// grid = (N2/64, 1), block = 448 threads (7 waves). Single kernel:
// phase 1 (Schur chain) once per column tile; phase 2's wave-group g emits
// output rows p = g, g+7, g+14 in one fused q-loop (T2 LDS reads and z
// global loads shared across the 3 rows); logdet finalized in-kernel by
// block 0 via a poison-immune ws flag handshake (all 256 blocks are
// co-resident at 1 block/CU, so the spin cannot deadlock).
__global__ __launch_bounds__(448) void fused_kernel(
    const float* __restrict__ l00r, const float* __restrict__ l00i,
    const float* __restrict__ l01r, const float* __restrict__ l01i,
    const float* __restrict__ l02r, const float* __restrict__ l02i,
    const float* __restrict__ l11r, const float* __restrict__ l11i,
    const float* __restrict__ l12r, const float* __restrict__ l12i,
    const float* __restrict__ l22r, const float* __restrict__ l22i,
    const float* __restrict__ zre,  const float* __restrict__ zim,
    float* __restrict__ out, void* __restrict__ ws)
{
    __shared__ float lds[L_TOT];
    const int t   = threadIdx.x;
    const int jl  = t & 63;
    const int j0  = blockIdx.x * 64;
    float ld = 0.f;

    // ================= phase 1: stage 0/1/2 per (u, jl) =================
    if (t < 256) {
        const int u = t >> 6;
        const int m = u * N2 + (j0 + jl);

        float i0r[4], i0i[4], t1r[4], t1i[4], p1r[4], p1i[4];
        float m1r = 0.f, m1i = 0.f;
#pragma unroll
        for (int k = 0; k < 4; ++k) {
            const int i = k * N1 + m;
            const float ar = l00r[i], ai = l00i[i];
            const float br = l01r[i], bi = l01i[i];
            const float d  = ar*ar + ai*ai;
            const float rd = 1.f / d;
            ld += 0.5f * logf(d);                   // log|lam00|
            const float xr = ar * rd, xi = -ai * rd;
            i0r[k] = xr; i0i[k] = xi;
            const float tr = br*xr - bi*xi;         // T1 = lam01/lam00
            const float ti = br*xi + bi*xr;
            t1r[k] = tr; t1i[k] = ti;
            m1r += br*tr + bi*ti;                   // conj(lam01)*T1
            m1i += br*ti - bi*tr;
        }
        const float s1r = l11r[m] - m1r;
        const float s1i = l11i[m] - m1i;
        const float ds1 = s1r*s1r + s1i*s1i;
        ld += 0.5f * logf(ds1);                     // log|S1|
        const float rds1 = 1.f / ds1;
        const float is1r = s1r * rds1, is1i = -s1i * rds1;
#pragma unroll
        for (int k = 0; k < 4; ++k) {
            p1r[k] = t1r[k]*is1r - t1i[k]*is1i;     // P1 = T1/S1
            p1i[k] = t1r[k]*is1i + t1i[k]*is1r;
        }

        // stage-2 B column: Bcol[a<4]=lam02[a*N1+m], Bcol[4]=lam12[m]
        float bcr[5], bci[5];
#pragma unroll
        for (int a = 0; a < 4; ++a) { bcr[a] = l02r[a*N1+m]; bci[a] = l02i[a*N1+m]; }
        bcr[4] = l12r[m]; bci[4] = l12i[m];

        // W = sum_{b<4} Bcol[b]*conj(T1[b]) - Bcol[4]
        float wr = -bcr[4], wi = -bci[4];
#pragma unroll
        for (int b = 0; b < 4; ++b) {
            wr += bcr[b]*t1r[b] + bci[b]*t1i[b];
            wi += bci[b]*t1r[b] - bcr[b]*t1i[b];
        }
        // T2 rows q = a*4+u
        float ur[5], ui[5];
#pragma unroll
        for (int a = 0; a < 4; ++a) {
            ur[a] = p1r[a]*wr - p1i[a]*wi + bcr[a]*i0r[a] - bci[a]*i0i[a];
            ui[a] = p1r[a]*wi + p1i[a]*wr + bcr[a]*i0i[a] + bci[a]*i0r[a];
        }
        {
            float vr = bcr[4]*is1r - bci[4]*is1i;   // Bcol[4]/S1
            float vi = bcr[4]*is1i + bci[4]*is1r;
#pragma unroll
            for (int b = 0; b < 4; ++b) {           // - Bcol[b]*conj(P1[b])
                vr -= bcr[b]*p1r[b] + bci[b]*p1i[b];
                vi -= bci[b]*p1r[b] - bcr[b]*p1i[b];
            }
            ur[4] = vr; ui[4] = vi;
        }
        float m2r = 0.f, m2i = 0.f;
#pragma unroll
        for (int a = 0; a < 5; ++a) {
            lds[L_T2R + (a*4+u)*64 + jl] = ur[a];
            lds[L_T2I + (a*4+u)*64 + jl] = ui[a];
            m2r += bcr[a]*ur[a] + bci[a]*ui[a];     // conj(B)*T2
            m2i += bcr[a]*ui[a] - bci[a]*ur[a];
        }
        lds[L_M2 + (0*4+u)*64 + jl] = m2r;
        lds[L_M2 + (1*4+u)*64 + jl] = m2i;
#pragma unroll
        for (int b = 0; b < 4; ++b) {
            SC(b,      u, jl) = t1r[b];  SC(4+b,  u, jl) = t1i[b];
            SC(8+b,    u, jl) = p1r[b];  SC(12+b, u, jl) = p1i[b];
            SC(16+b,   u, jl) = i0r[b];  SC(20+b, u, jl) = i0i[b];
        }
        SC(24, u, jl) = is1r;  SC(25, u, jl) = is1i;
    }
    __syncthreads();

    // ================= phase 1.5: S2 per column =================
    if (t < 64) {
        float s2r = l22r[j0 + t], s2i = l22i[j0 + t];
#pragma unroll
        for (int u = 0; u < 4; ++u) {
            s2r -= lds[L_M2 + (0*4+u)*64 + t];
            s2i -= lds[L_M2 + (1*4+u)*64 + t];
        }
        const float ds2  = s2r*s2r + s2i*s2i;
        const float rds2 = 1.f / ds2;
        lds[L_IS2R + t] =  s2r * rds2;
        lds[L_IS2I + t] = -s2i * rds2;
        ld += 0.5f * logf(ds2);                     // log|S2|
    }
    __syncthreads();

    // ===== phase 2: rows p = g, g+7, g+14; lane = (h: q-parity, c: col pair) =====
    const int g  = t >> 6;                          // wave group 0..6
    const int l  = t & 63;
    const int h  = l >> 5;                          // q parity
    const int c  = l & 31;                          // column-pair index
    const int c2 = 2*c;
    const int j2 = j0 + c2;                         // first of the 2 columns

    const float is2r0 = lds[L_IS2R + c2],   is2r1 = lds[L_IS2R + c2+1];
    const float is2i0 = lds[L_IS2I + c2],   is2i1 = lds[L_IS2I + c2+1];

    SLOT_PREP(0, g)
    SLOT_PREP(1, g + 7)
    SLOT_PREP(2, g + 14)

#pragma unroll
    for (int qi = 0; qi < 11; ++qi) {
        const int q = 2*qi + h;
        if (q >= 21) continue;
        float tr0=0.f, tr1=0.f, ti0=0.f, ti1=0.f;
        if (q < 20) {
            tr0 = lds[L_T2R + q*64 + c2];  tr1 = lds[L_T2R + q*64 + c2+1];
            ti0 = lds[L_T2I + q*64 + c2];  ti1 = lds[L_T2I + q*64 + c2+1];
        }
        const float2 zr2 = *(const float2*)(zre + q*N2 + j2);
        const float2 zi2 = *(const float2*)(zim + q*N2 + j2);
        SLOT_Q(0);
        SLOT_Q(1);
        SLOT_Q(2);
    }

    SLOT_ZSTORE(0);
    SLOT_ZSTORE(1);
    SLOT_ZSTORE(2);

    // ======== logdet: block reduction + in-kernel cross-block finalize ========
    double* wsd              = (double*)ws;                         // partials
    unsigned* wflag          = (unsigned*)((char*)ws + 4096);       // flags
    volatile unsigned* wref  = (volatile unsigned*)((char*)ws + 8192); // never written
    {
        float v = ld;
#pragma unroll
        for (int off = 32; off > 0; off >>= 1) v += __shfl_down(v, off, 64);
        __syncthreads();                            // LDS reuse guard
        if (jl == 0) lds[L_RED + g] = v;
        __syncthreads();
        if (t == 0) {
            double s = 0.0;
#pragma unroll
            for (int w = 0; w < 7; ++w) s += (double)lds[L_RED + w];
            wsd[blockIdx.x] = s;
            __threadfence();                        // partial visible device-wide
            atomicExch(&wflag[blockIdx.x], ~(*wref));   // tag != poison, always
        }
    }

    // block 0, wave 0: wait for all 256 partials, reduce, write OUT_LD
    if (blockIdx.x == 0 && t < 64) {
        const unsigned tag = ~(*wref);
#pragma unroll
        for (int s4 = 0; s4 < 4; ++s4) {
            const int slot = t + 64*s4;
            while (atomicOr(&wflag[slot], 0u) != tag)
                __builtin_amdgcn_s_sleep(8);
        }
        __threadfence();
        double v = 0.0;
#pragma unroll
        for (int s4 = 0; s4 < 4; ++s4) {            // device-scope 2x32b reads
            const int slot = t + 64*s4;
            const unsigned lo = atomicOr((unsigned*)&wsd[slot],     0u);
            const unsigned hi = atomicOr((unsigned*)&wsd[slot] + 1, 0u);
            v += __hiloint2double((int)hi, (int)lo);
        }
#pragma unroll
        for (int off = 32; off > 0; off >>= 1) v += __shfl_down(v, off, 64);
        if (t == 0) out[OUT_LD] = (float)v;
    }
}

extern "C" void kernel_launch(void* const* d_in, const int* in_sizes, int n_in,
                              void* d_out, int out_size, void* d_ws, size_t ws_size,
                              hipStream_t stream)
{
    const float* l00r = (const float*)d_in[0];
    const float* l00i = (const float*)d_in[1];
    const float* l01r = (const float*)d_in[2];
    const float* l01i = (const float*)d_in[3];
    const float* l02r = (const float*)d_in[4];
    const float* l02i = (const float*)d_in[5];
    const float* l11r = (const float*)d_in[6];
    const float* l11i = (const float*)d_in[7];
    const float* l12r = (const float*)d_in[8];
    const float* l12i = (const float*)d_in[9];
    const float* l22r = (const float*)d_in[10];
    const float* l22i = (const float*)d_in[11];
    const float* zre  = (const float*)d_in[12];
    const float* zim  = (const float*)d_in[13];
    float* out        = (float*)d_out;

    fused_kernel<<<dim3(N2/64, 1), dim3(448), 0, stream>>>(
        l00r,l00i,l01r,l01i,l02r,l02i,l11r,l11i,l12r,l12i,l22r,l22i,
        zre,zim, out, d_ws);
}

// Round 6
// 108.733 us; speedup vs baseline: 1.0739x; 1.0739x over previous
//
#include <hip/hip_runtime.h>

#define N2 16384
#define N1 65536

// ---- output layout (float offsets) ----
#define OUT_AIM 7225344         // 21*21*N2
#define OUT_LD  14450688        // 2*21*21*N2
#define OUT_ZRE 14450689
#define OUT_ZIM 14794753        // OUT_ZRE + 21*N2

// ---- LDS layout (float offsets), TILE_J = 64 ----
#define L_T2R  0                // [20][64]
#define L_T2I  1280
#define L_M2   2560             // [c:2][u:4][64]
#define L_SC   3072             // [idx:26][u:4][64]
//   idx 0..3  t1r[b], 4..7  t1i[b], 8..11 p1r[b], 12..15 p1i[b],
//   idx 16..19 i0r[k], 20..23 i0i[k], 24 is1r, 25 is1i
#define L_IS2R 9728             // [64]
#define L_IS2I 9792
#define L_RED  9856             // [7]
#define L_TOT  9864             // 38.5 KB

#define SC(idx, u, jl) lds[L_SC + (((idx)*4 + (u)) * 64) + (jl)]

// ---- workspace: 256 doubles (per-block logdet partials). ws is re-poisoned
// by the harness each iteration (unconditional 268MB fill — proven R0/R1),
// and every slot is overwritten by fused_kernel before finalize reads it.
// Visibility: kernel-boundary release/acquire on the same stream.

// packed 8-byte non-temporal store of two adjacent floats
#define NTST2(addr, v0, v1) do {                                   \
    union { float f[2]; long L; } _u; _u.f[0] = (v0); _u.f[1] = (v1); \
    __builtin_nontemporal_store(_u.L, (long*)(addr)); } while (0)

// ---- phase-2 per-row-slot machinery (3 rows per wave-group) ----
// Slot state is kept in individually named registers (no runtime-indexed
// arrays -> no scratch). p is wave-uniform per slot.
#define SLOT_PREP(s, P)                                                       \
    const int  p##s    = (P);                                                 \
    const bool is20_##s = (p##s == 20);                                       \
    const int  ap_##s  = p##s >> 2, up_##s = p##s & 3;                        \
    float ppr0_##s=0.f, ppi0_##s=0.f, ppr1_##s=0.f, ppi1_##s=0.f;             \
    float par0_##s=0.f, pai0_##s=0.f, par1_##s=0.f, pai1_##s=0.f;             \
    if (!is20_##s) {                                                          \
        const float tpr0 = lds[L_T2R + p##s*64 + c2], tpr1 = lds[L_T2R + p##s*64 + c2+1]; \
        const float tpi0 = lds[L_T2I + p##s*64 + c2], tpi1 = lds[L_T2I + p##s*64 + c2+1]; \
        ppr0_##s = tpr0*is2r0 - tpi0*is2i0;  ppi0_##s = tpr0*is2i0 + tpi0*is2r0; \
        ppr1_##s = tpr1*is2r1 - tpi1*is2i1;  ppi1_##s = tpr1*is2i1 + tpi1*is2r1; \
        if (ap_##s < 4) {                                                     \
            par0_##s = SC(8+ap_##s,  up_##s, c2);   pai0_##s = SC(12+ap_##s, up_##s, c2);   \
            par1_##s = SC(8+ap_##s,  up_##s, c2+1); pai1_##s = SC(12+ap_##s, up_##s, c2+1); \
        }                                                                     \
    }                                                                         \
    float zar0_##s=0.f, zai0_##s=0.f, zar1_##s=0.f, zai1_##s=0.f;

#define SLOT_Q(s) do {                                                        \
    float ar0, ai0, ar1, ai1;                                                 \
    if (is20_##s) {                                                           \
        if (q < 20) {                                                         \
            ar0 = -(tr0*is2r0 - ti0*is2i0);  ai0 = tr0*is2i0 + ti0*is2r0;     \
            ar1 = -(tr1*is2r1 - ti1*is2i1);  ai1 = tr1*is2i1 + ti1*is2r1;     \
        } else { ar0=is2r0; ai0=is2i0; ar1=is2r1; ai1=is2i1; }                \
    } else if (q < 20) {                                                      \
        ar0 = ppr0_##s*tr0 + ppi0_##s*ti0;  ai0 = ppi0_##s*tr0 - ppr0_##s*ti0;\
        ar1 = ppr1_##s*tr1 + ppi1_##s*ti1;  ai1 = ppi1_##s*tr1 - ppr1_##s*ti1;\
        if ((q & 3) == up_##s) {            /* + A1[ap][q>>2] scatter */      \
            const int b = q >> 2;                                             \
            if (ap_##s < 4) {                                                 \
                if (b < 4) {                                                  \
                    const float tbr0 = SC(b, up_##s, c2),   tbi0 = SC(4+b, up_##s, c2);   \
                    const float tbr1 = SC(b, up_##s, c2+1), tbi1 = SC(4+b, up_##s, c2+1); \
                    ar0 += par0_##s*tbr0 + pai0_##s*tbi0;  ai0 += pai0_##s*tbr0 - par0_##s*tbi0; \
                    ar1 += par1_##s*tbr1 + pai1_##s*tbi1;  ai1 += pai1_##s*tbr1 - par1_##s*tbi1; \
                    if (b == ap_##s) {             /* + 1/lam00 */            \
                        ar0 += SC(16+ap_##s, up_##s, c2);   ai0 += SC(20+ap_##s, up_##s, c2);   \
                        ar1 += SC(16+ap_##s, up_##s, c2+1); ai1 += SC(20+ap_##s, up_##s, c2+1); \
                    }                                                         \
                } else { ar0 -= par0_##s; ai0 -= pai0_##s; ar1 -= par1_##s; ai1 -= pai1_##s; } \
            } else {                                                          \
                if (b < 4) {                       /* -conj(P1[b]) */         \
                    ar0 -= SC(8+b, up_##s, c2);   ai0 += SC(12+b, up_##s, c2);   \
                    ar1 -= SC(8+b, up_##s, c2+1); ai1 += SC(12+b, up_##s, c2+1); \
                } else {                           /* 1/S1 */                 \
                    ar0 += SC(24, up_##s, c2);   ai0 += SC(25, up_##s, c2);   \
                    ar1 += SC(24, up_##s, c2+1); ai1 += SC(25, up_##s, c2+1); \
                }                                                             \
            }                                                                 \
        }                                                                     \
    } else { ar0 = -ppr0_##s; ai0 = -ppi0_##s; ar1 = -ppr1_##s; ai1 = -ppi1_##s; } \
    NTST2(out + (p##s*21+q)*N2 + j2,           ar0, ar1);                     \
    NTST2(out + OUT_AIM + (p##s*21+q)*N2 + j2, ai0, ai1);                     \
    zar0_##s += zr2.x*ar0 - zi2.x*ai0;  zai0_##s += zr2.x*ai0 + zi2.x*ar0;    \
    zar1_##s += zr2.y*ar1 - zi2.y*ai1;  zai1_##s += zr2.y*ai1 + zi2.y*ar1;    \
} while (0)

#define SLOT_ZSTORE(s) do {                                                   \
    float a0 = zar0_##s, b0 = zai0_##s, a1 = zar1_##s, b1 = zai1_##s;         \
    a0 += __shfl_xor(a0, 32, 64);  b0 += __shfl_xor(b0, 32, 64);              \
    a1 += __shfl_xor(a1, 32, 64);  b1 += __shfl_xor(b1, 32, 64);              \
    const int src = l >> 1;                                                   \
    const float e_r = __shfl(a0, src, 64), o_r = __shfl(a1, src, 64);         \
    const float e_i = __shfl(b0, src, 64), o_i = __shfl(b1, src, 64);         \
    const float zvr = (l & 1) ? o_r : e_r;                                    \
    const float zvi = (l & 1) ? o_i : e_i;                                    \
    __builtin_nontemporal_store(zvr, out + OUT_ZRE + p##s*N2 + j0 + l);       \
    __builtin_nontemporal_store(zvi, out + OUT_ZIM + p##s*N2 + j0 + l);       \
} while (0)

// grid = (N2/64, 1), block = 448 threads (7 waves).
// Phase 1 (Schur chain) once per column tile; phase 2's wave-group g emits
// output rows p = g, g+7, g+14 in one fused q-loop (T2 LDS reads and z
// global loads shared across the 3 rows). Logdet partial -> ws (double),
// reduced by the tiny finalize dispatch (stream-ordered).
__global__ __launch_bounds__(448) void fused_kernel(
    const float* __restrict__ l00r, const float* __restrict__ l00i,
    const float* __restrict__ l01r, const float* __restrict__ l01i,
    const float* __restrict__ l02r, const float* __restrict__ l02i,
    const float* __restrict__ l11r, const float* __restrict__ l11i,
    const float* __restrict__ l12r, const float* __restrict__ l12i,
    const float* __restrict__ l22r, const float* __restrict__ l22i,
    const float* __restrict__ zre,  const float* __restrict__ zim,
    float* __restrict__ out, double* __restrict__ ld_partial)
{
    __shared__ float lds[L_TOT];
    const int t   = threadIdx.x;
    const int jl  = t & 63;
    const int j0  = blockIdx.x * 64;
    float ld = 0.f;

    // ================= phase 1: stage 0/1/2 per (u, jl) =================
    if (t < 256) {
        const int u = t >> 6;
        const int m = u * N2 + (j0 + jl);

        float i0r[4], i0i[4], t1r[4], t1i[4], p1r[4], p1i[4];
        float m1r = 0.f, m1i = 0.f;
#pragma unroll
        for (int k = 0; k < 4; ++k) {
            const int i = k * N1 + m;
            const float ar = l00r[i], ai = l00i[i];
            const float br = l01r[i], bi = l01i[i];
            const float d  = ar*ar + ai*ai;
            const float rd = 1.f / d;
            ld += 0.5f * logf(d);                   // log|lam00|
            const float xr = ar * rd, xi = -ai * rd;
            i0r[k] = xr; i0i[k] = xi;
            const float tr = br*xr - bi*xi;         // T1 = lam01/lam00
            const float ti = br*xi + bi*xr;
            t1r[k] = tr; t1i[k] = ti;
            m1r += br*tr + bi*ti;                   // conj(lam01)*T1
            m1i += br*ti - bi*tr;
        }
        const float s1r = l11r[m] - m1r;
        const float s1i = l11i[m] - m1i;
        const float ds1 = s1r*s1r + s1i*s1i;
        ld += 0.5f * logf(ds1);                     // log|S1|
        const float rds1 = 1.f / ds1;
        const float is1r = s1r * rds1, is1i = -s1i * rds1;
#pragma unroll
        for (int k = 0; k < 4; ++k) {
            p1r[k] = t1r[k]*is1r - t1i[k]*is1i;     // P1 = T1/S1
            p1i[k] = t1r[k]*is1i + t1i[k]*is1r;
        }

        // stage-2 B column: Bcol[a<4]=lam02[a*N1+m], Bcol[4]=lam12[m]
        float bcr[5], bci[5];
#pragma unroll
        for (int a = 0; a < 4; ++a) { bcr[a] = l02r[a*N1+m]; bci[a] = l02i[a*N1+m]; }
        bcr[4] = l12r[m]; bci[4] = l12i[m];

        // W = sum_{b<4} Bcol[b]*conj(T1[b]) - Bcol[4]
        float wr = -bcr[4], wi = -bci[4];
#pragma unroll
        for (int b = 0; b < 4; ++b) {
            wr += bcr[b]*t1r[b] + bci[b]*t1i[b];
            wi += bci[b]*t1r[b] - bcr[b]*t1i[b];
        }
        // T2 rows q = a*4+u
        float ur[5], ui[5];
#pragma unroll
        for (int a = 0; a < 4; ++a) {
            ur[a] = p1r[a]*wr - p1i[a]*wi + bcr[a]*i0r[a] - bci[a]*i0i[a];
            ui[a] = p1r[a]*wi + p1i[a]*wr + bcr[a]*i0i[a] + bci[a]*i0r[a];
        }
        {
            float vr = bcr[4]*is1r - bci[4]*is1i;   // Bcol[4]/S1
            float vi = bcr[4]*is1i + bci[4]*is1r;
#pragma unroll
            for (int b = 0; b < 4; ++b) {           // - Bcol[b]*conj(P1[b])
                vr -= bcr[b]*p1r[b] + bci[b]*p1i[b];
                vi -= bci[b]*p1r[b] - bcr[b]*p1i[b];
            }
            ur[4] = vr; ui[4] = vi;
        }
        float m2r = 0.f, m2i = 0.f;
#pragma unroll
        for (int a = 0; a < 5; ++a) {
            lds[L_T2R + (a*4+u)*64 + jl] = ur[a];
            lds[L_T2I + (a*4+u)*64 + jl] = ui[a];
            m2r += bcr[a]*ur[a] + bci[a]*ui[a];     // conj(B)*T2
            m2i += bcr[a]*ui[a] - bci[a]*ur[a];
        }
        lds[L_M2 + (0*4+u)*64 + jl] = m2r;
        lds[L_M2 + (1*4+u)*64 + jl] = m2i;
#pragma unroll
        for (int b = 0; b < 4; ++b) {
            SC(b,      u, jl) = t1r[b];  SC(4+b,  u, jl) = t1i[b];
            SC(8+b,    u, jl) = p1r[b];  SC(12+b, u, jl) = p1i[b];
            SC(16+b,   u, jl) = i0r[b];  SC(20+b, u, jl) = i0i[b];
        }
        SC(24, u, jl) = is1r;  SC(25, u, jl) = is1i;
    }
    __syncthreads();

    // ================= phase 1.5: S2 per column =================
    if (t < 64) {
        float s2r = l22r[j0 + t], s2i = l22i[j0 + t];
#pragma unroll
        for (int u = 0; u < 4; ++u) {
            s2r -= lds[L_M2 + (0*4+u)*64 + t];
            s2i -= lds[L_M2 + (1*4+u)*64 + t];
        }
        const float ds2  = s2r*s2r + s2i*s2i;
        const float rds2 = 1.f / ds2;
        lds[L_IS2R + t] =  s2r * rds2;
        lds[L_IS2I + t] = -s2i * rds2;
        ld += 0.5f * logf(ds2);                     // log|S2|
    }
    __syncthreads();

    // ===== phase 2: rows p = g, g+7, g+14; lane = (h: q-parity, c: col pair) =====
    const int g  = t >> 6;                          // wave group 0..6
    const int l  = t & 63;
    const int h  = l >> 5;                          // q parity
    const int c  = l & 31;                          // column-pair index
    const int c2 = 2*c;
    const int j2 = j0 + c2;                         // first of the 2 columns

    const float is2r0 = lds[L_IS2R + c2],   is2r1 = lds[L_IS2R + c2+1];
    const float is2i0 = lds[L_IS2I + c2],   is2i1 = lds[L_IS2I + c2+1];

    SLOT_PREP(0, g)
    SLOT_PREP(1, g + 7)
    SLOT_PREP(2, g + 14)

#pragma unroll
    for (int qi = 0; qi < 11; ++qi) {
        const int q = 2*qi + h;
        if (q >= 21) continue;
        float tr0=0.f, tr1=0.f, ti0=0.f, ti1=0.f;
        if (q < 20) {
            tr0 = lds[L_T2R + q*64 + c2];  tr1 = lds[L_T2R + q*64 + c2+1];
            ti0 = lds[L_T2I + q*64 + c2];  ti1 = lds[L_T2I + q*64 + c2+1];
        }
        const float2 zr2 = *(const float2*)(zre + q*N2 + j2);
        const float2 zi2 = *(const float2*)(zim + q*N2 + j2);
        SLOT_Q(0);
        SLOT_Q(1);
        SLOT_Q(2);
    }

    SLOT_ZSTORE(0);
    SLOT_ZSTORE(1);
    SLOT_ZSTORE(2);

    // ================= logdet block reduction -> ws partial =================
    {
        float v = ld;
#pragma unroll
        for (int off = 32; off > 0; off >>= 1) v += __shfl_down(v, off, 64);
        __syncthreads();                            // LDS reuse guard
        if (jl == 0) lds[L_RED + g] = v;
        __syncthreads();
        if (t == 0) {
            double s = 0.0;
#pragma unroll
            for (int w = 0; w < 7; ++w) s += (double)lds[L_RED + w];
            ld_partial[blockIdx.x] = s;
        }
    }
}

// 1 block, 256 threads: reduce the 256 double partials, write OUT_LD.
__global__ __launch_bounds__(256) void finalize_kernel(
    const double* __restrict__ part, float* __restrict__ out)
{
    double v = part[threadIdx.x];
#pragma unroll
    for (int off = 32; off > 0; off >>= 1) v += __shfl_down(v, off, 64);
    __shared__ double wsum[4];
    if ((threadIdx.x & 63) == 0) wsum[threadIdx.x >> 6] = v;
    __syncthreads();
    if (threadIdx.x == 0)
        out[OUT_LD] = (float)(wsum[0] + wsum[1] + wsum[2] + wsum[3]);
}

extern "C" void kernel_launch(void* const* d_in, const int* in_sizes, int n_in,
                              void* d_out, int out_size, void* d_ws, size_t ws_size,
                              hipStream_t stream)
{
    const float* l00r = (const float*)d_in[0];
    const float* l00i = (const float*)d_in[1];
    const float* l01r = (const float*)d_in[2];
    const float* l01i = (const float*)d_in[3];
    const float* l02r = (const float*)d_in[4];
    const float* l02i = (const float*)d_in[5];
    const float* l11r = (const float*)d_in[6];
    const float* l11i = (const float*)d_in[7];
    const float* l12r = (const float*)d_in[8];
    const float* l12i = (const float*)d_in[9];
    const float* l22r = (const float*)d_in[10];
    const float* l22i = (const float*)d_in[11];
    const float* zre  = (const float*)d_in[12];
    const float* zim  = (const float*)d_in[13];
    float*  out        = (float*)d_out;
    double* ld_partial = (double*)d_ws;             // 256 doubles, rewritten each call

    fused_kernel<<<dim3(N2/64, 1), dim3(448), 0, stream>>>(
        l00r,l00i,l01r,l01i,l02r,l02i,l11r,l11i,l12r,l12i,l22r,l22i,
        zre,zim, out, ld_partial);
    finalize_kernel<<<1, 256, 0, stream>>>(ld_partial, out);
}